// Round 1
// baseline (754.321 us; speedup 1.0000x reference)
//
#include <hip/hip_runtime.h>
#include <cstdint>
#include <cstddef>

#define BATCH 8
#define HH 56
#define WW 56
#define HWSZ 3136      // HH*WW
#define P4SZ 784       // HWSZ/4
#define GCHUNK 112     // row-chunks per batch for kglobal
#define GROWS (HWSZ / GCHUNK)   // 28 rows per chunk

// ---- monotone float <-> uint mapping for atomicMax on floats ----
__device__ __forceinline__ unsigned fmap(float f) {
    unsigned u = __float_as_uint(f);
    return (u & 0x80000000u) ? ~u : (u | 0x80000000u);
}
__device__ __forceinline__ float funmap(unsigned u) {
    if (u == 0u) return -INFINITY;   // memset sentinel (never produced by fmap)
    return (u & 0x80000000u) ? __uint_as_float(u ^ 0x80000000u) : __uint_as_float(~u);
}

__device__ __forceinline__ void fmax4(float4& m, float4 x, float s) {
    m.x = fmaxf(m.x, x.x * s);
    m.y = fmaxf(m.y, x.y * s);
    m.z = fmaxf(m.z, x.z * s);
    m.w = fmaxf(m.w, x.w * s);
}

// ============================================================================
// Kernel 1 — global branch, row-streaming.
// out[b][ch][p] = max_j sim[b][j][p] * seg[b][ch][j], ch in {0,1}
// Grid: BATCH*GCHUNK = 896 blocks of 256. Block (b,chunk) streams GROWS=28
// consecutive rows FULLY COALESCED (lane t reads row[t], row[256+t],
// row[512+t]; threads 0..15 also row[768+t]) and keeps the per-column max of
// both channels in registers (2ch x ~3.06 float4/thread). Cross-chunk
// reduction via atomicMax on fmap'ed uints (same trick as klocal).
// Replaces the old column-stripe kernel whose wave-loads touched 16
// discontiguous 64B segments at 12.5KB stride (half-used L2 lines split
// across XCDs -> ~2x over-fetch + poor DRAM locality).
// ============================================================================
__global__ __launch_bounds__(256) void kglobal(const float4* __restrict__ sim4,
                                               const float* __restrict__ seg,
                                               unsigned* __restrict__ accg) {
    const int blk   = blockIdx.x;
    const int b     = blk / GCHUNK;
    const int chunk = blk - b * GCHUNK;
    const int j0    = chunk * GROWS;
    const int t     = threadIdx.x;

    const float* seg0 = seg + (size_t)(b * 2 + 0) * HWSZ;
    const float* seg1 = seg + (size_t)(b * 2 + 1) * HWSZ;

    const float4* base = sim4 + ((size_t)b * HWSZ + j0) * P4SZ;

    float4 g0[4], g1[4];
    #pragma unroll
    for (int i = 0; i < 4; ++i) {
        g0[i] = make_float4(-INFINITY, -INFINITY, -INFINITY, -INFINITY);
        g1[i] = g0[i];
    }

    const bool tail = (t < (P4SZ - 3 * 256));   // t < 16 owns column 768+t

    #pragma unroll 2
    for (int jr = 0; jr < GROWS; ++jr) {
        const float v0 = seg0[j0 + jr];   // uniform -> scalar loads
        const float v1 = seg1[j0 + jr];
        const float4* row = base + (size_t)jr * P4SZ;
        float4 x0 = row[t];
        float4 x1 = row[256 + t];
        float4 x2 = row[512 + t];
        fmax4(g0[0], x0, v0); fmax4(g1[0], x0, v1);
        fmax4(g0[1], x1, v0); fmax4(g1[1], x1, v1);
        fmax4(g0[2], x2, v0); fmax4(g1[2], x2, v1);
        if (tail) {
            float4 x3 = row[768 + t];
            fmax4(g0[3], x3, v0); fmax4(g1[3], x3, v1);
        }
    }

    unsigned* a0 = accg + (size_t)(b * 2 + 0) * HWSZ;
    unsigned* a1 = accg + (size_t)(b * 2 + 1) * HWSZ;
    #pragma unroll
    for (int i = 0; i < 4; ++i) {
        const int c = i * 256 + t;
        if (c < P4SZ) {
            atomicMax(&a0[c * 4 + 0], fmap(g0[i].x));
            atomicMax(&a0[c * 4 + 1], fmap(g0[i].y));
            atomicMax(&a0[c * 4 + 2], fmap(g0[i].z));
            atomicMax(&a0[c * 4 + 3], fmap(g0[i].w));
            atomicMax(&a1[c * 4 + 0], fmap(g1[i].x));
            atomicMax(&a1[c * 4 + 1], fmap(g1[i].y));
            atomicMax(&a1[c * 4 + 2], fmap(g1[i].z));
            atomicMax(&a1[c * 4 + 3], fmap(g1[i].w));
        }
    }
}

// ============================================================================
// Kernel 2 — local branch (UNCHANGED, harness-verified). One wave per (b,j)
// row of prev_sim (3136 floats in registers: 12 float4 + 1 scalar per lane).
// Computes row min and row top-4, wave-merges, then atomically maxes the
// >=cut elements (scaled per channel) into acc and the scale*min term into Ml.
// ============================================================================
__global__ __launch_bounds__(256) void klocal(const float* __restrict__ simf,
                                              const float* __restrict__ seg,
                                              unsigned* __restrict__ acc,
                                              unsigned* __restrict__ Ml) {
    const int wave = (blockIdx.x << 2) | (threadIdx.x >> 6);
    const int lane = threadIdx.x & 63;
    const int b = wave / HWSZ;
    const int j = wave - b * HWSZ;

    const float* rowf = simf + (size_t)wave * HWSZ;
    const float4* row4 = (const float4*)rowf;

    float4 x[12];
    #pragma unroll
    for (int k = 0; k < 12; ++k) x[k] = row4[k * 64 + lane];
    const float xs = rowf[3072 + lane];

    float mn = INFINITY;
    float t0 = -INFINITY, t1 = -INFINITY, t2 = -INFINITY, t3 = -INFINITY;

    // branchless sorted insert (keeps t0>=t1>=t2>=t3 = top-4 of inserted set)
    #define INS(v) do { \
        float _v = (v); \
        float _r0 = fmaxf(t0, _v), _s0 = fminf(t0, _v); \
        float _r1 = fmaxf(t1, _s0), _s1 = fminf(t1, _s0); \
        float _r2 = fmaxf(t2, _s1), _s2 = fminf(t2, _s1); \
        float _r3 = fmaxf(t3, _s2); \
        t0 = _r0; t1 = _r1; t2 = _r2; t3 = _r3; } while (0)

    #pragma unroll
    for (int k = 0; k < 12; ++k) {
        mn = fminf(mn, fminf(fminf(x[k].x, x[k].y), fminf(x[k].z, x[k].w)));
        INS(x[k].x); INS(x[k].y); INS(x[k].z); INS(x[k].w);
    }
    mn = fminf(mn, xs);
    INS(xs);

    // wave butterfly: all lanes converge to row min and row top-4
    #pragma unroll
    for (int off = 32; off; off >>= 1) {
        mn = fminf(mn, __shfl_xor(mn, off));
        float o0 = __shfl_xor(t0, off);
        float o1 = __shfl_xor(t1, off);
        float o2 = __shfl_xor(t2, off);
        float o3 = __shfl_xor(t3, off);
        INS(o0); INS(o1); INS(o2); INS(o3);
    }
    #undef INS

    const float cut = t3;   // 4th largest raw value of the row
    const float sc0 = seg[(size_t)(b * 2 + 0) * HWSZ + j];
    const float sc1 = seg[(size_t)(b * 2 + 1) * HWSZ + j];

    unsigned* l0 = acc + (size_t)(b * 2 + 0) * HWSZ;
    unsigned* l1 = acc + (size_t)(b * 2 + 1) * HWSZ;

    #pragma unroll
    for (int k = 0; k < 12; ++k) {
        const int pb = (k * 64 + lane) * 4;
        if (x[k].x >= cut) { atomicMax(&l0[pb + 0], fmap(x[k].x * sc0)); atomicMax(&l1[pb + 0], fmap(x[k].x * sc1)); }
        if (x[k].y >= cut) { atomicMax(&l0[pb + 1], fmap(x[k].y * sc0)); atomicMax(&l1[pb + 1], fmap(x[k].y * sc1)); }
        if (x[k].z >= cut) { atomicMax(&l0[pb + 2], fmap(x[k].z * sc0)); atomicMax(&l1[pb + 2], fmap(x[k].z * sc1)); }
        if (x[k].w >= cut) { atomicMax(&l0[pb + 3], fmap(x[k].w * sc0)); atomicMax(&l1[pb + 3], fmap(x[k].w * sc1)); }
    }
    if (xs >= cut) {
        const int p = 3072 + lane;
        atomicMax(&l0[p], fmap(xs * sc0));
        atomicMax(&l1[p], fmap(xs * sc1));
    }

    // per-row min term: block-reduce (4 waves, all same b) then one atomic
    __shared__ float mred[8];
    if (lane == 0) {
        const int w = threadIdx.x >> 6;
        mred[w * 2 + 0] = mn * sc0;
        mred[w * 2 + 1] = mn * sc1;
    }
    __syncthreads();
    if (threadIdx.x == 0) {
        float m0 = fmaxf(fmaxf(mred[0], mred[2]), fmaxf(mred[4], mred[6]));
        float m1 = fmaxf(fmaxf(mred[1], mred[3]), fmaxf(mred[5], mred[7]));
        atomicMax(&Ml[b * 2 + 0], fmap(m0));
        atomicMax(&Ml[b * 2 + 1], fmap(m1));
    }
}

// ============================================================================
// Kernel 3 — finalize all four channels: unmap global accumulator (ch 0/1),
// unmap local accumulator + min-term (ch 2/3).
// ============================================================================
__global__ __launch_bounds__(256) void kfinal(const unsigned* __restrict__ accg,
                                              const unsigned* __restrict__ accl,
                                              const unsigned* __restrict__ Ml,
                                              float* __restrict__ out) {
    const int tid = blockIdx.x * 256 + threadIdx.x;
    if (tid >= BATCH * HWSZ) return;
    const int b = tid / HWSZ;
    const int p = tid - b * HWSZ;

    float* ob = out + (size_t)b * 4 * HWSZ;
    ob[0 * HWSZ + p] = funmap(accg[(size_t)(b * 2 + 0) * HWSZ + p]);
    ob[1 * HWSZ + p] = funmap(accg[(size_t)(b * 2 + 1) * HWSZ + p]);

    const float M0 = funmap(Ml[b * 2 + 0]);
    const float M1 = funmap(Ml[b * 2 + 1]);
    ob[2 * HWSZ + p] = fmaxf(M0, funmap(accl[(size_t)(b * 2 + 0) * HWSZ + p]));
    ob[3 * HWSZ + p] = fmaxf(M1, funmap(accl[(size_t)(b * 2 + 1) * HWSZ + p]));
}

extern "C" void kernel_launch(void* const* d_in, const int* in_sizes, int n_in,
                              void* d_out, int out_size, void* d_ws, size_t ws_size,
                              hipStream_t stream) {
    const float* init_sim = (const float*)d_in[0];
    const float* prev_sim = (const float*)d_in[1];
    const float* init_seg = (const float*)d_in[2];
    const float* prev_seg = (const float*)d_in[3];
    float* out = (float*)d_out;

    unsigned* accg = (unsigned*)d_ws;                        // BATCH*2*HWSZ
    unsigned* accl = accg + (size_t)BATCH * 2 * HWSZ;        // BATCH*2*HWSZ
    unsigned* Ml   = accl + (size_t)BATCH * 2 * HWSZ;        // BATCH*2
    const size_t clear_bytes =
        ((size_t)BATCH * 2 * HWSZ * 2 + BATCH * 2) * sizeof(unsigned);

    hipMemsetAsync(d_ws, 0, clear_bytes, stream);

    kglobal<<<BATCH * GCHUNK, 256, 0, stream>>>((const float4*)init_sim, init_seg, accg);
    klocal<<<(BATCH * HWSZ) / 4, 256, 0, stream>>>(prev_sim, prev_seg, accl, Ml);
    kfinal<<<(BATCH * HWSZ + 255) / 256, 256, 0, stream>>>(accg, accl, Ml, out);
}